// Round 1
// baseline (2501.251 us; speedup 1.0000x reference)
//
#include <hip/hip_runtime.h>
#include <stdint.h>

#define D 800
#define NA 20000
#define NB 24000
#define NG 256

typedef unsigned short u16;
typedef __attribute__((ext_vector_type(8))) short s8v;
typedef __attribute__((ext_vector_type(4))) short s4v;
typedef __attribute__((ext_vector_type(4))) float f4v;

__device__ __forceinline__ float b2f(u16 u) {
  union { float f; uint32_t i; } x; x.i = ((uint32_t)u) << 16; return x.f;
}
__device__ __forceinline__ u16 f2b(float f) {
  union { float f; uint32_t i; } x; x.f = f;
  uint32_t r = x.i + 0x7fffu + ((x.i >> 16) & 1u);
  return (u16)(r >> 16);
}

__device__ __forceinline__ void async_cp16(const u16* g, u16* l) {
  __builtin_amdgcn_global_load_lds(
      (const __attribute__((address_space(1))) unsigned int*)(const void*)g,
      (__attribute__((address_space(3))) unsigned int*)(void*)l, 16, 0, 0);
}

// ---------------- f32 -> bf16 cast (float4 vectorized) ----------------------
__global__ __launch_bounds__(256) void castk(const float* __restrict__ x,
                                             u16* __restrict__ y, int n4) {
  const int i = blockIdx.x * 256 + threadIdx.x;
  if (i >= n4) return;
  const float4 v = ((const float4*)x)[i];
  ushort4 o;
  o.x = f2b(v.x); o.y = f2b(v.y); o.z = f2b(v.z); o.w = f2b(v.w);
  ((ushort4*)y)[i] = o;
}

// ---------------- GEMM: C[M,800] = A[M,800](bf16) @ W (+f32 bias) -----------
__global__ __launch_bounds__(256) void gemm_bt(
    const u16* __restrict__ A, const u16* __restrict__ BT,
    const float* __restrict__ bias, int M, int mode, float bscale,
    u16* __restrict__ outb, float* __restrict__ outf, u16* __restrict__ prev)
{
  __shared__ u16 sA[128 * 32];
  __shared__ u16 sB[128 * 32];
  const int tid  = threadIdx.x;
  const int row0 = blockIdx.x * 128;
  const int col0 = blockIdx.y * 128;
  const int ldRow = tid >> 2;
  const int ldCol = (tid & 3) * 8;
  const int w = tid >> 6, lane = tid & 63;
  const int wm = (w & 1) * 64, wn = (w >> 1) * 64;
  const int lr = lane & 15, quad = lane >> 4;

  f4v acc[4][4] = {};

  int ra = row0 + ldRow;      if (ra > M - 1) ra = M - 1;
  int rb = row0 + ldRow + 64; if (rb > M - 1) rb = M - 1;
  const u16* arow0 = A  + (size_t)ra * D + ldCol;
  const u16* arow1 = A  + (size_t)rb * D + ldCol;
  const u16* brow0 = BT + (size_t)(col0 + ldRow) * D + ldCol;
  const u16* brow1 = BT + (size_t)(col0 + ldRow + 64) * D + ldCol;
  u16* la0 = &sA[tid * 8];
  u16* la1 = &sA[2048 + tid * 8];
  u16* lb0 = &sB[tid * 8];
  u16* lb1 = &sB[2048 + tid * 8];

  for (int kt = 0; kt < 25; ++kt) {
    const int k0 = kt * 32;
    async_cp16(arow0 + k0, la0);
    async_cp16(arow1 + k0, la1);
    async_cp16(brow0 + k0, lb0);
    async_cp16(brow1 + k0, lb1);
    __syncthreads();
    s8v af[4], bf[4];
#pragma unroll
    for (int i = 0; i < 4; ++i)
      af[i] = *(const s8v*)&sA[(wm + i * 16 + lr) * 32 + quad * 8];
#pragma unroll
    for (int j = 0; j < 4; ++j)
      bf[j] = *(const s8v*)&sB[(wn + j * 16 + lr) * 32 + quad * 8];
#pragma unroll
    for (int i = 0; i < 4; ++i)
#pragma unroll
      for (int j = 0; j < 4; ++j)
        acc[i][j] = __builtin_amdgcn_mfma_f32_16x16x32_bf16(af[i], bf[j], acc[i][j], 0, 0, 0);
    __syncthreads();
  }

#pragma unroll
  for (int i = 0; i < 4; ++i) {
#pragma unroll
    for (int j = 0; j < 4; ++j) {
      const int col = col0 + wn + j * 16 + lr;
      if (col >= D) continue;
      const float bv = bias[col];
#pragma unroll
      for (int r = 0; r < 4; ++r) {
        const int row = row0 + wm + i * 16 + quad * 4 + r;
        if (row >= M) continue;
        const size_t idx = (size_t)row * D + col;
        const float v = acc[i][j][r];
        if (mode == 0) {
          outb[idx] = f2b(v + bv);
        } else if (mode == 1) {
          const float p = b2f(prev[idx]);
          prev[idx] = f2b(0.8f * p + 0.2f * (v + bv));
        } else if (mode == 2) {
          outf[idx] = v + bscale * bv;
        } else {
          outf[idx] += v + bscale * bv;
        }
      }
    }
  }
}

// -------- transpose+cast Ws[w] (f32 800x800 k-major) -> WT[w] (bf16 896x800)
__global__ void transpose_w(const float* __restrict__ W, u16* __restrict__ WT) {
  __shared__ u16 t[32][33];
  const int wm = blockIdx.z;
  const int k0 = blockIdx.x * 32, n0 = blockIdx.y * 32;
  const float* Wm = W + (size_t)wm * D * D;
  u16* Om = WT + (size_t)wm * 896 * D;
  const int tx = threadIdx.x, ty = threadIdx.y;
#pragma unroll
  for (int i = ty; i < 32; i += 8) {
    const int n = n0 + tx;
    t[i][tx] = (n < D) ? f2b(Wm[(size_t)(k0 + i) * D + n]) : (u16)0;
  }
  __syncthreads();
#pragma unroll
  for (int i = ty; i < 32; i += 8) {
    Om[(size_t)(n0 + i) * D + (k0 + tx)] = t[tx][i];
  }
}

// ------ e_pre[b] += Ah[ba0] + Ah[ba1] + Cu[bg]  (in-place, ushort8/lane) ----
__global__ __launch_bounds__(256) void bond_combine(
    u16* __restrict__ epre, const u16* __restrict__ Ah, const u16* __restrict__ Cu,
    const int* __restrict__ ba, const int* __restrict__ bg)
{
  const int t = blockIdx.x * 256 + threadIdx.x;
  if (t >= NB * 100) return;
  const int b = t / 100;
  const int c = t - b * 100;
  const int a0 = ba[b * 2], a1 = ba[b * 2 + 1], g = bg[b];
  const size_t off = (size_t)c * 8;
  u16* re = epre + (size_t)b * D + off;
  const s8v ve = *(const s8v*)re;
  const s8v v0 = *(const s8v*)(Ah + (size_t)a0 * D + off);
  const s8v v1 = *(const s8v*)(Ah + (size_t)a1 * D + off);
  const s8v vg = *(const s8v*)(Cu + (size_t)g * D + off);
  s8v o;
#pragma unroll
  for (int l = 0; l < 8; ++l)
    o[l] = (short)f2b(b2f((u16)ve[l]) + b2f((u16)v0[l]) + b2f((u16)v1[l]) + b2f((u16)vg[l]));
  *(s8v*)re = o;
}

// ------- two-stage column stats: partial (no atomics) + final reduce --------
// thread owns 8 consecutive cols (c<100), ushort8 loads; part[y][1600]
__global__ __launch_bounds__(128) void col_part(
    const u16* __restrict__ x, int M, int rpb, float* __restrict__ part)
{
  const int c = threadIdx.x;
  if (c >= 100) return;
  const int r0 = blockIdx.y * rpb;
  int r1 = r0 + rpb; if (r1 > M) r1 = M;
  float s[8] = {}, ss[8] = {};
  for (int r = r0; r < r1; ++r) {
    const s8v v = *(const s8v*)(x + (size_t)r * D + c * 8);
#pragma unroll
    for (int l = 0; l < 8; ++l) { const float f = b2f((u16)v[l]); s[l] += f; ss[l] += f * f; }
  }
  float* p = part + (size_t)blockIdx.y * 1600 + c * 8;
#pragma unroll
  for (int l = 0; l < 8; ++l) { p[l] = s[l]; p[800 + l] = ss[l]; }
}

__global__ __launch_bounds__(256) void col_fin(
    const float* __restrict__ part, int ny, float* __restrict__ sums)
{
  const int idx = blockIdx.x * 256 + threadIdx.x;
  if (idx >= 1600) return;
  float s = 0.f;
  for (int y = 0; y < ny; ++y) s += part[(size_t)y * 1600 + idx];
  sums[idx] = s;
}

// ---------------- legacy column sums (kept for small f32 u-path) ------------
__global__ __launch_bounds__(256) void col_stats(
    const void* __restrict__ x, int isf32, int M, int rpb, float* __restrict__ sums)
{
  const int col = blockIdx.x * 256 + threadIdx.x;
  if (col >= D) return;
  const int r0 = blockIdx.y * rpb;
  int r1 = r0 + rpb; if (r1 > M) r1 = M;
  float s = 0.f, ss = 0.f;
  if (isf32) {
    const float* xf = (const float*)x;
    for (int r = r0; r < r1; ++r) { const float v = xf[(size_t)r * D + col]; s += v; ss += v * v; }
  } else {
    const u16* xb = (const u16*)x;
    for (int r = r0; r < r1; ++r) { const float v = b2f(xb[(size_t)r * D + col]); s += v; ss += v * v; }
  }
  atomicAdd(&sums[col], s);
  atomicAdd(&sums[D + col], ss);
}

// ---- bn+relu, thread owns 8 cols: ushort8 in, 2x float4 out ----------------
__global__ __launch_bounds__(128) void bn_relu8(
    const u16* __restrict__ x, int M, int rpb, const float* __restrict__ sums,
    const float* __restrict__ gamma, const float* __restrict__ beta, float* __restrict__ out)
{
  const int c = threadIdx.x;
  if (c >= 100) return;
  const float invM = 1.f / (float)M;
  float gg[8], bb[8];
#pragma unroll
  for (int l = 0; l < 8; ++l) {
    const int col = c * 8 + l;
    const float mean = sums[col] * invM;
    float var = sums[800 + col] * invM - mean * mean;
    if (var < 0.f) var = 0.f;
    const float rs = rsqrtf(var + 1e-5f);
    gg[l] = gamma[col] * rs;
    bb[l] = beta[col] - mean * gg[l];
  }
  const int r0 = blockIdx.y * rpb;
  int r1 = r0 + rpb; if (r1 > M) r1 = M;
  for (int r = r0; r < r1; ++r) {
    const s8v v = *(const s8v*)(x + (size_t)r * D + c * 8);
    f4v o0, o1;
#pragma unroll
    for (int l = 0; l < 4; ++l) {
      const float y0 = b2f((u16)v[l]) * gg[l] + bb[l];
      o0[l] = (y0 > 0.f) ? y0 : 0.f;
      const float y1 = b2f((u16)v[4 + l]) * gg[4 + l] + bb[4 + l];
      o1[l] = (y1 > 0.f) ? y1 : 0.f;
    }
    float* orow = out + (size_t)r * D + c * 8;
    *(f4v*)orow = o0;
    *(f4v*)(orow + 4) = o1;
  }
}

// ---------------- legacy bn_relu (kept for small f32 u-path) ----------------
__global__ __launch_bounds__(256) void bn_relu(
    const void* __restrict__ x, int isf32, int M, int rpb, const float* __restrict__ sums,
    const float* __restrict__ gamma, const float* __restrict__ beta, float* __restrict__ out)
{
  const int col = blockIdx.x * 256 + threadIdx.x;
  if (col >= D) return;
  const float invM = 1.f / (float)M;
  const float mean = sums[col] * invM;
  float var = sums[D + col] * invM - mean * mean;
  if (var < 0.f) var = 0.f;
  const float rs = rsqrtf(var + 1e-5f);
  const float g = gamma[col] * rs;
  const float b = beta[col] - mean * g;
  const int r0 = blockIdx.y * rpb;
  int r1 = r0 + rpb; if (r1 > M) r1 = M;
  if (isf32) {
    const float* xf = (const float*)x;
    for (int r = r0; r < r1; ++r) {
      const float y = xf[(size_t)r * D + col] * g + b;
      out[(size_t)r * D + col] = (y > 0.f) ? y : 0.f;
    }
  } else {
    const u16* xb = (const u16*)x;
    for (int r = r0; r < r1; ++r) {
      const float y = b2f(xb[(size_t)r * D + col]) * g + b;
      out[(size_t)r * D + col] = (y > 0.f) ? y : 0.f;
    }
  }
}

// ------- gated mailbox aggregation + a2a + g2a (thread owns 4 cols) ---------
__global__ __launch_bounds__(256) void atom_update(
    u16* __restrict__ hpre, const u16* __restrict__ Dh, const u16* __restrict__ Eh,
    const float* __restrict__ en, const u16* __restrict__ Fu,
    const int* __restrict__ ab, const int* __restrict__ ba, const int* __restrict__ ag)
{
  const int i = blockIdx.x;
  __shared__ int sb[4], so[4], sg[1];
  const int t = threadIdx.x;
  if (t < 4) {
    const int b = ab[i * 4 + t];
    sb[t] = b;
    const int p0 = ba[b * 2], p1 = ba[b * 2 + 1];
    so[t] = (p0 != i) ? p0 : p1;
  }
  if (t == 4) sg[0] = ag[i];
  __syncthreads();
  if (t >= 200) return;
  const int j0 = t * 4;
  float num[4] = {0.f, 0.f, 0.f, 0.f}, den[4] = {0.f, 0.f, 0.f, 0.f};
#pragma unroll
  for (int k = 0; k < 4; ++k) {
    const f4v ev = *(const f4v*)(en + (size_t)sb[k] * D + j0);
    const s4v eo = *(const s4v*)(Eh + (size_t)so[k] * D + j0);
#pragma unroll
    for (int l = 0; l < 4; ++l) {
      const float s = 1.f / (1.f + __expf(-ev[l]));
      num[l] += s * b2f((u16)eo[l]);
      den[l] += s;
    }
  }
  const s4v dv = *(const s4v*)(Dh + (size_t)i * D + j0);
  const s4v fv = *(const s4v*)(Fu + (size_t)sg[0] * D + j0);
  s4v o;
#pragma unroll
  for (int l = 0; l < 4; ++l)
    o[l] = (short)f2b(b2f((u16)dv[l]) + num[l] / (den[l] + 1e-6f) + b2f((u16)fv[l]));
  *(s4v*)(hpre + (size_t)i * D + j0) = o;
}

// --- c = 1/(|d1-d2|+1); cd1 = c*d1; cd2 = c*d2 (ushort8/lane) ---------------
__global__ __launch_bounds__(256) void cross_cd(
    const u16* __restrict__ D1, const u16* __restrict__ D2,
    u16* __restrict__ c1, u16* __restrict__ c2)
{
  const int t = blockIdx.x * 256 + threadIdx.x;
  if (t >= NA * 100) return;
  const size_t off = (size_t)t * 8;
  const s8v v1 = *(const s8v*)(D1 + off);
  const s8v v2 = *(const s8v*)(D2 + off);
  s8v o1, o2;
#pragma unroll
  for (int l = 0; l < 8; ++l) {
    const float d1 = b2f((u16)v1[l]), d2 = b2f((u16)v2[l]);
    const float cc = 1.f / (fabsf(d1 - d2) + 1.f);
    o1[l] = (short)f2b(cc * d1);
    o2[l] = (short)f2b(cc * d2);
  }
  *(s8v*)(c1 + off) = o1;
  *(s8v*)(c2 + off) = o2;
}

// ============ counting-sort based segment mean (4 pipelines fused) ==========
// which: 0=h1(ag1,NA) 1=h2(ag2,NA) 2=e1(bg1,NB) 3=e2(bg2,NB)
__global__ void seg_histo(const int* __restrict__ s0, const int* __restrict__ s1,
                          const int* __restrict__ s2, const int* __restrict__ s3,
                          int* __restrict__ cnt) {
  const int which = blockIdx.y;
  const int* s = (which == 0) ? s0 : (which == 1) ? s1 : (which == 2) ? s2 : s3;
  const int n = (which < 2) ? NA : NB;
  const int i = blockIdx.x * 256 + threadIdx.x;
  if (i < n) atomicAdd(&cnt[which * NG + s[i]], 1);
}

__global__ __launch_bounds__(256) void seg_scan(
    const int* __restrict__ cnt, int* __restrict__ start, int* __restrict__ cursor) {
  const int which = blockIdx.x;
  __shared__ int buf[NG];
  const int t = threadIdx.x;
  const int v = cnt[which * NG + t];
  buf[t] = v;
  __syncthreads();
  int sum = 0;
  for (int i = 0; i < t; ++i) sum += buf[i];
  start[which * 257 + t] = sum;
  cursor[which * NG + t] = sum;
  if (t == NG - 1) start[which * 257 + NG] = sum + v;
}

__global__ void seg_scatter(const int* __restrict__ s0, const int* __restrict__ s1,
                            const int* __restrict__ s2, const int* __restrict__ s3,
                            int* __restrict__ cursor, int* __restrict__ order) {
  const int which = blockIdx.y;
  const int* s = (which == 0) ? s0 : (which == 1) ? s1 : (which == 2) ? s2 : s3;
  const int n = (which < 2) ? NA : NB;
  const int i = blockIdx.x * 256 + threadIdx.x;
  if (i < n) {
    const int pos = atomicAdd(&cursor[which * NG + s[i]], 1);
    order[which * NB + pos] = i;
  }
}

// block (g, which): mean over this graph's rows; float4 reads, no atomics
__global__ __launch_bounds__(256) void seg_reduce(
    const float* __restrict__ x0, const float* __restrict__ x1,
    const float* __restrict__ x2, const float* __restrict__ x3,
    const int* __restrict__ order, const int* __restrict__ start,
    float* __restrict__ means) {
  const int which = blockIdx.y;
  const float* x = (which == 0) ? x0 : (which == 1) ? x1 : (which == 2) ? x2 : x3;
  const int* ord = order + which * NB;
  const int g = blockIdx.x;
  const int i0 = start[which * 257 + g];
  const int i1 = start[which * 257 + g + 1];
  const int t = threadIdx.x;
  if (t >= 200) return;
  float a0 = 0.f, a1 = 0.f, a2 = 0.f, a3 = 0.f;
  for (int i = i0; i < i1; ++i) {
    const f4v v = *(const f4v*)(x + (size_t)ord[i] * D + t * 4);
    a0 += v[0]; a1 += v[1]; a2 += v[2]; a3 += v[3];
  }
  const int cc = i1 - i0;
  const float inv = 1.f / (float)(cc > 1 ? cc : 1);
  f4v o; o[0] = a0 * inv; o[1] = a1 * inv; o[2] = a2 * inv; o[3] = a3 * inv;
  *(f4v*)(means + ((size_t)which * NG + g) * D + t * 4) = o;
}

// hbar = bf16(mean_h1+mean_h2), ebar = bf16(mean_e1+mean_e2)  (float4/lane)
__global__ __launch_bounds__(256) void bar_prep(
    const float* __restrict__ means, u16* __restrict__ hbar, u16* __restrict__ ebar) {
  const int i4 = blockIdx.x * 256 + threadIdx.x;
  if (i4 >= NG * 200) return;
  const f4v m1 = ((const f4v*)means)[i4];
  const f4v m2 = ((const f4v*)(means + (size_t)NG * D))[i4];
  const f4v e1 = ((const f4v*)(means + (size_t)2 * NG * D))[i4];
  const f4v e2 = ((const f4v*)(means + (size_t)3 * NG * D))[i4];
  ushort4 ho, eo;
  ho.x = f2b(m1[0] + m2[0]); ho.y = f2b(m1[1] + m2[1]);
  ho.z = f2b(m1[2] + m2[2]); ho.w = f2b(m1[3] + m2[3]);
  eo.x = f2b(e1[0] + e2[0]); eo.y = f2b(e1[1] + e2[1]);
  eo.z = f2b(e1[2] + e2[2]); eo.w = f2b(e1[3] + e2[3]);
  ((ushort4*)hbar)[i4] = ho;
  ((ushort4*)ebar)[i4] = eo;
}

extern "C" void kernel_launch(void* const* d_in, const int* in_sizes, int n_in,
                              void* d_out, int out_size, void* d_ws, size_t ws_size,
                              hipStream_t stream)
{
  const float* h   = (const float*)d_in[0];
  const float* e   = (const float*)d_in[1];
  const float* h2  = (const float*)d_in[2];
  const float* e2  = (const float*)d_in[3];
  const float* u   = (const float*)d_in[4];
  const float* Ws  = (const float*)d_in[5];
  const float* bs  = (const float*)d_in[6];
  const float* gm  = (const float*)d_in[7];
  const float* bt  = (const float*)d_in[8];
  const int* ba1 = (const int*)d_in[9];
  const int* ab1 = (const int*)d_in[10];
  const int* ag1 = (const int*)d_in[11];
  const int* bg1 = (const int*)d_in[12];
  const int* ba2 = (const int*)d_in[13];
  const int* ab2 = (const int*)d_in[14];
  const int* ag2 = (const int*)d_in[15];
  const int* bg2 = (const int*)d_in[16];
  char* ws = (char*)d_ws;
  char* ob = (char*)d_out;

  // ---- workspace layout (bytes) ----
  const size_t WT   = 0;                    // 14,336,000
  const size_t CB   = 14336000;             // 38,400,000 cast buf / cd1 / sort bufs
  const size_t E1P  = 52736000;             // 38,400,000 (later h1pre)
  const size_t E2P  = 91136000;             // (later h2pre)
  const size_t CD2  = 129536000;            // 32,000,000
  const size_t CUo  = 161536000;
  const size_t FUo  = 161945600;
  const size_t UB   = 162355200;
  const size_t F32Z = 162764800;            // zeroed fp32 scratch base
  const size_t ST_E1 = F32Z;
  const size_t ST_E2 = F32Z + 6400;
  const size_t ST_H1 = F32Z + 12800;
  const size_t ST_H2 = F32Z + 19200;
  const size_t ST_U  = F32Z + 25600;
  const size_t ZLEN  = 32000;               // just the 5 stats blocks
  const size_t MEANS = F32Z + 32000;        // 4*256*800*4 = 3,276,800
  const size_t UPRE  = MEANS + 3276800;     // 819,200
  const size_t HBAR  = UPRE + 819200;       // bf16 409,600
  const size_t EBAR  = HBAR + 409600;
  // sort scratch inside CB region (dead after the mode-1 GEMMs)
  const size_t ORD  = CB;                   // 4*24000*4 = 384,000
  const size_t CNTI = CB + 400000;          // 4*256*4 = 4,096 (memset-zeroed)
  const size_t STRT = CB + 404496 + 3504;   // 4*257*4 = 4,112  (aligned region)
  const size_t CURS = CB + 416000;          // 4,096
  // col-stat partials: 500*1600*4 = 3,200,000 bytes inside CB region.
  // Temporally safe: e-stats run after e2-cast is consumed, before cross_cd
  // writes cd1; h-stats run after gemm(cd1) consumed cd1; sort scratch is
  // only touched after h-stats complete.
  const size_t PART = CB + 4000000;

  u16* wt  = (u16*)(ws + WT);
  u16* cb  = (u16*)(ws + CB);
  u16* e1p = (u16*)(ws + E1P);
  u16* e2p = (u16*)(ws + E2P);
  u16* cd2 = (u16*)(ws + CD2);
  u16* cu  = (u16*)(ws + CUo);
  u16* fu  = (u16*)(ws + FUo);
  u16* ub  = (u16*)(ws + UB);
  u16* h1p = e1p;
  u16* h2p = e2p;
  u16* cd1 = cb;
  float* part = (float*)(ws + PART);

  float* o_h1 = (float*)ob;
  float* o_e1 = (float*)(ob + 64000000);
  float* o_h2 = (float*)(ob + 140800000);
  float* o_e2 = (float*)(ob + 204800000);
  float* o_u  = (float*)(ob + 281600000);
  u16* eh1s = (u16*)ob;
  u16* dh1s = (u16*)(ob + 32000000);
  u16* eh2s = (u16*)(ob + 140800000);
  u16* dh2s = (u16*)(ob + 172800000);
  u16* ah1s = (u16*)(ob + 64000000);
  u16* ah2s = (u16*)(ob + 204800000);

  auto gemm = [&](const u16* A, int widx, int M, int mode, float bsc,
                  u16* outb, float* outf, u16* prev) {
    dim3 grid((unsigned)((M + 127) / 128), 7);
    gemm_bt<<<grid, 256, 0, stream>>>(A, wt + (size_t)widx * 896 * D,
                                      bs + (size_t)widx * D, M, mode, bsc,
                                      outb, outf, prev);
  };

  hipMemsetAsync(ws + F32Z, 0, ZLEN, stream);
  transpose_w<<<dim3(25, 28, 10), dim3(32, 8), 0, stream>>>(Ws, wt);

  // u-linears (shared by both halves)
  castk<<<200, 256, 0, stream>>>(u, ub, NG * D / 4);
  gemm(ub, 2, NG, 0, 1.f, cu, nullptr, nullptr);   // Cu
  gemm(ub, 5, NG, 0, 1.f, fu, nullptr, nullptr);   // Fu

  // h/e linears (cast buffer reused sequentially)
  castk<<<15625, 256, 0, stream>>>(h, cb, NA * D / 4);
  gemm(cb, 0, NA, 0, 1.f, ah1s, nullptr, nullptr); // Ah1
  gemm(cb, 3, NA, 0, 1.f, dh1s, nullptr, nullptr); // Dh1
  gemm(cb, 4, NA, 0, 1.f, eh1s, nullptr, nullptr); // Eh1
  castk<<<15625, 256, 0, stream>>>(h2, cb, NA * D / 4);
  gemm(cb, 0, NA, 0, 1.f, ah2s, nullptr, nullptr); // Ah2
  gemm(cb, 3, NA, 0, 1.f, dh2s, nullptr, nullptr); // Dh2
  gemm(cb, 4, NA, 0, 1.f, eh2s, nullptr, nullptr); // Eh2
  castk<<<18750, 256, 0, stream>>>(e, cb, NB * D / 4);
  gemm(cb, 1, NB, 0, 1.f, e1p, nullptr, nullptr);  // Be1
  castk<<<18750, 256, 0, stream>>>(e2, cb, NB * D / 4);
  gemm(cb, 1, NB, 0, 1.f, e2p, nullptr, nullptr);  // Be2

  // bond update + BN + relu -> e1n/e2n
  bond_combine<<<9375, 256, 0, stream>>>(e1p, ah1s, cu, ba1, bg1);
  bond_combine<<<9375, 256, 0, stream>>>(e2p, ah2s, cu, ba2, bg2);
  col_part<<<dim3(1, 500), 128, 0, stream>>>(e1p, NB, 48, part);
  col_fin<<<7, 256, 0, stream>>>(part, 500, (float*)(ws + ST_E1));
  col_part<<<dim3(1, 500), 128, 0, stream>>>(e2p, NB, 48, part);
  col_fin<<<7, 256, 0, stream>>>(part, 500, (float*)(ws + ST_E2));
  bn_relu8<<<dim3(1, 500), 128, 0, stream>>>(e1p, NB, 48, (float*)(ws + ST_E1), gm, bt, o_e1);
  bn_relu8<<<dim3(1, 500), 128, 0, stream>>>(e2p, NB, 48, (float*)(ws + ST_E2), gm, bt, o_e2);

  // atom update
  atom_update<<<NA, 256, 0, stream>>>(h1p, dh1s, eh1s, o_e1, fu, ab1, ba1, ag1);
  atom_update<<<NA, 256, 0, stream>>>(h2p, dh2s, eh2s, o_e2, fu, ab2, ba2, ag2);

  // cross messages mixed in-place via GEMM epilogue
  cross_cd<<<7813, 256, 0, stream>>>(dh1s, dh2s, cd1, cd2);
  gemm(cd2, 9, NA, 1, 1.f, nullptr, nullptr, h1p); // h1 = 0.8 h1 + 0.2 m21
  gemm(cd1, 9, NA, 1, 1.f, nullptr, nullptr, h2p); // h2 = 0.8 h2 + 0.2 m12

  // BN + relu -> h1n/h2n
  col_part<<<dim3(1, 500), 128, 0, stream>>>(h1p, NA, 40, part);
  col_fin<<<7, 256, 0, stream>>>(part, 500, (float*)(ws + ST_H1));
  col_part<<<dim3(1, 500), 128, 0, stream>>>(h2p, NA, 40, part);
  col_fin<<<7, 256, 0, stream>>>(part, 500, (float*)(ws + ST_H2));
  bn_relu8<<<dim3(1, 500), 128, 0, stream>>>(h1p, NA, 40, (float*)(ws + ST_H1), gm + D, bt + D, o_h1);
  bn_relu8<<<dim3(1, 500), 128, 0, stream>>>(h2p, NA, 40, (float*)(ws + ST_H2), gm + D, bt + D, o_h2);

  // segment means via counting sort (CB region is dead now)
  hipMemsetAsync(ws + CNTI, 0, 4096, stream);
  seg_histo<<<dim3(94, 4), 256, 0, stream>>>(ag1, ag2, bg1, bg2, (int*)(ws + CNTI));
  seg_scan<<<4, 256, 0, stream>>>((int*)(ws + CNTI), (int*)(ws + STRT), (int*)(ws + CURS));
  seg_scatter<<<dim3(94, 4), 256, 0, stream>>>(ag1, ag2, bg1, bg2,
                                               (int*)(ws + CURS), (int*)(ws + ORD));
  seg_reduce<<<dim3(NG, 4), 256, 0, stream>>>(o_h1, o_h2, o_e1, o_e2,
                                              (int*)(ws + ORD), (int*)(ws + STRT),
                                              (float*)(ws + MEANS));
  bar_prep<<<200, 256, 0, stream>>>((float*)(ws + MEANS), (u16*)(ws + HBAR), (u16*)(ws + EBAR));

  // u_pre = u@W8 + b8 + hbar12@W6 + 2*b6 + ebar12@W7 + 2*b7 (fp32 accum)
  gemm(ub,                8, NG, 2, 1.f, nullptr, (float*)(ws + UPRE), nullptr);
  gemm((u16*)(ws + HBAR), 6, NG, 3, 2.f, nullptr, (float*)(ws + UPRE), nullptr);
  gemm((u16*)(ws + EBAR), 7, NG, 3, 2.f, nullptr, (float*)(ws + UPRE), nullptr);

  col_stats<<<dim3(4, 1), 256, 0, stream>>>((float*)(ws + UPRE), 1, NG, 256, (float*)(ws + ST_U));
  bn_relu<<<dim3(4, 1), 256, 0, stream>>>((float*)(ws + UPRE), 1, NG, 256, (float*)(ws + ST_U),
                                          gm + 2 * D, bt + 2 * D, o_u);
}

// Round 2
// 2110.119 us; speedup vs baseline: 1.1854x; 1.1854x over previous
//
#include <hip/hip_runtime.h>
#include <stdint.h>

#define D 800
#define NA 20000
#define NB 24000
#define NG 256

typedef unsigned short u16;
typedef __attribute__((ext_vector_type(8))) short s8v;
typedef __attribute__((ext_vector_type(4))) short s4v;
typedef __attribute__((ext_vector_type(4))) float f4v;

__device__ __forceinline__ float b2f(u16 u) {
  union { float f; uint32_t i; } x; x.i = ((uint32_t)u) << 16; return x.f;
}
__device__ __forceinline__ u16 f2b(float f) {
  union { float f; uint32_t i; } x; x.f = f;
  uint32_t r = x.i + 0x7fffu + ((x.i >> 16) & 1u);
  return (u16)(r >> 16);
}

__device__ __forceinline__ void async_cp16(const u16* g, u16* l) {
  __builtin_amdgcn_global_load_lds(
      (const __attribute__((address_space(1))) unsigned int*)(const void*)g,
      (__attribute__((address_space(3))) unsigned int*)(void*)l, 16, 0, 0);
}

// ---------------- f32 -> bf16 cast (float4 vectorized) ----------------------
__global__ __launch_bounds__(256) void castk(const float* __restrict__ x,
                                             u16* __restrict__ y, int n4) {
  const int i = blockIdx.x * 256 + threadIdx.x;
  if (i >= n4) return;
  const float4 v = ((const float4*)x)[i];
  ushort4 o;
  o.x = f2b(v.x); o.y = f2b(v.y); o.z = f2b(v.z); o.w = f2b(v.w);
  ((ushort4*)y)[i] = o;
}

// ---------------- GEMM: C[M,800] = A[M,800](bf16) @ W (+f32 bias) -----------
// BK=64, XOR-swizzled LDS (st-16B within 128B rows), batched over
// (half, weight, coltile) via blockIdx.y. mode: 0=bf16 out, 1=0.8*prev+0.2*(v+b)
// with fused column stats into st, 2=f32 out, 3=f32 +=.
__global__ __launch_bounds__(256) void gemm_bt(
    const u16* __restrict__ A0, const u16* __restrict__ A1,
    const u16* __restrict__ wt, const float* __restrict__ bs,
    int M, int mode, float bscale,
    u16* o0, u16* o1, u16* o2, u16* o3, u16* o4, u16* o5,
    float* outf, u16* prev0, u16* prev1,
    float* st0, float* st1,
    int nwh, int w0, int w1, int w2)
{
  __shared__ u16 sA[128 * 64];
  __shared__ u16 sB[128 * 64];
  const int tid = threadIdx.x;
  const int ytiles = nwh * 7;
  const int half = blockIdx.y / ytiles;
  const int yy = blockIdx.y - half * ytiles;
  const int wsel = yy / 7;
  const int ct = yy - wsel * 7;
  const int widx = (wsel == 0) ? w0 : (wsel == 1) ? w1 : w2;
  const u16* A = half ? A1 : A0;
  const u16* BT = wt + (size_t)widx * 896 * D;
  const float* bias = bs + (size_t)widx * D;
  const int row0 = blockIdx.x * 128;
  const int col0 = ct * 128;

  const int w = tid >> 6, lane = tid & 63;
  const int wm = (w & 1) * 64, wn = (w >> 1) * 64;
  const int lr = lane & 15, quad = lane >> 4;

  // staging geometry: thread covers (row b*32+sr, col-bytes scb..scb+15)
  const int sr  = tid >> 3;          // 0..31
  const int scb = (tid & 7) * 16;    // linear dest col-byte in [0,128)
  const int swz = (sr & 7) << 4;
  const int scs = scb ^ swz;         // pre-swizzled SOURCE col-byte

  uint32_t aoff[4], boff[4];
#pragma unroll
  for (int b = 0; b < 4; ++b) {
    int ra = row0 + b * 32 + sr; if (ra > M - 1) ra = M - 1;
    aoff[b] = (uint32_t)ra * (D * 2) + scs;
    boff[b] = (uint32_t)(col0 + b * 32 + sr) * (D * 2) + scs;
  }
  u16* la = &sA[tid * 8];
  u16* lb = &sB[tid * 8];

  f4v acc[4][4] = {};
  const int rdsw = (lr & 7) << 4;    // reader-side swizzle

  // 12 full K-steps of 64
  for (int kt = 0; kt < 12; ++kt) {
    const uint32_t kb = (uint32_t)kt * 128;
#pragma unroll
    for (int b = 0; b < 4; ++b) {
      async_cp16((const u16*)((const char*)A  + aoff[b] + kb), la + b * 2048);
      async_cp16((const u16*)((const char*)BT + boff[b] + kb), lb + b * 2048);
    }
    __syncthreads();
#pragma unroll
    for (int kk = 0; kk < 2; ++kk) {
      s8v af[4], bf[4];
      const int cbyte = (kk * 64 + quad * 16) ^ rdsw;
#pragma unroll
      for (int i = 0; i < 4; ++i)
        af[i] = *(const s8v*)((const char*)sA + (wm + i * 16 + lr) * 128 + cbyte);
#pragma unroll
      for (int j = 0; j < 4; ++j)
        bf[j] = *(const s8v*)((const char*)sB + (wn + j * 16 + lr) * 128 + cbyte);
#pragma unroll
      for (int i = 0; i < 4; ++i)
#pragma unroll
        for (int j = 0; j < 4; ++j)
          acc[i][j] = __builtin_amdgcn_mfma_f32_16x16x32_bf16(af[i], bf[j], acc[i][j], 0, 0, 0);
    }
    __syncthreads();
  }
  // tail K-step (k=768..799): stage full width (over-read is into valid
  // adjacent memory and never consumed), compute kk=0 only
  {
    const uint32_t kb = 12u * 128u;
#pragma unroll
    for (int b = 0; b < 4; ++b) {
      async_cp16((const u16*)((const char*)A  + aoff[b] + kb), la + b * 2048);
      async_cp16((const u16*)((const char*)BT + boff[b] + kb), lb + b * 2048);
    }
    __syncthreads();
    s8v af[4], bf[4];
    const int cbyte = (quad * 16) ^ rdsw;
#pragma unroll
    for (int i = 0; i < 4; ++i)
      af[i] = *(const s8v*)((const char*)sA + (wm + i * 16 + lr) * 128 + cbyte);
#pragma unroll
    for (int j = 0; j < 4; ++j)
      bf[j] = *(const s8v*)((const char*)sB + (wn + j * 16 + lr) * 128 + cbyte);
#pragma unroll
    for (int i = 0; i < 4; ++i)
#pragma unroll
      for (int j = 0; j < 4; ++j)
        acc[i][j] = __builtin_amdgcn_mfma_f32_16x16x32_bf16(af[i], bf[j], acc[i][j], 0, 0, 0);
  }

  const int os = half * 3 + wsel;
  u16* outb = (os == 0) ? o0 : (os == 1) ? o1 : (os == 2) ? o2
            : (os == 3) ? o3 : (os == 4) ? o4 : o5;
  u16* prev = half ? prev1 : prev0;

  if (mode == 1) {
    float* sums = half ? st1 : st0;
    __syncthreads();                     // done with sA as bf16 tiles
    float* red = (float*)sA;             // 2048 floats scratch
    const int contrib = (w & 1) * 4 + quad;
#pragma unroll
    for (int j = 0; j < 4; ++j) {
      const int colloc = wn + j * 16 + lr;
      const int col = col0 + colloc;
      float s = 0.f, ss = 0.f;
      if (col < D) {
        const float bv = bias[col];
#pragma unroll
        for (int i = 0; i < 4; ++i) {
#pragma unroll
          for (int r = 0; r < 4; ++r) {
            const int row = row0 + wm + i * 16 + quad * 4 + r;
            if (row < M) {
              const size_t idx = (size_t)row * D + col;
              const float p = b2f(prev[idx]);
              const float nv = 0.8f * p + 0.2f * (acc[i][j][r] + bv);
              prev[idx] = f2b(nv);
              s += nv; ss += nv * nv;
            }
          }
        }
      }
      red[contrib * 256 + colloc] = s;
      red[contrib * 256 + 128 + colloc] = ss;
    }
    __syncthreads();
    const int stat = tid >> 7, colloc = tid & 127;
    float v = 0.f;
#pragma unroll
    for (int c = 0; c < 8; ++c) v += red[c * 256 + stat * 128 + colloc];
    const int col = col0 + colloc;
    if (col < D) atomicAdd(sums + stat * 800 + col, v);
    return;
  }

#pragma unroll
  for (int i = 0; i < 4; ++i) {
#pragma unroll
    for (int j = 0; j < 4; ++j) {
      const int col = col0 + wn + j * 16 + lr;
      if (col >= D) continue;
      const float bv = bias[col];
#pragma unroll
      for (int r = 0; r < 4; ++r) {
        const int row = row0 + wm + i * 16 + quad * 4 + r;
        if (row >= M) continue;
        const size_t idx = (size_t)row * D + col;
        const float v = acc[i][j][r];
        if (mode == 0) {
          outb[idx] = f2b(v + bv);
        } else if (mode == 2) {
          outf[idx] = v + bscale * bv;
        } else {
          outf[idx] += v + bscale * bv;
        }
      }
    }
  }
}

// -------- transpose+cast Ws[w] (f32 800x800 k-major) -> WT[w] (bf16 896x800)
__global__ void transpose_w(const float* __restrict__ W, u16* __restrict__ WT) {
  __shared__ u16 t[32][33];
  const int wm = blockIdx.z;
  const int k0 = blockIdx.x * 32, n0 = blockIdx.y * 32;
  const float* Wm = W + (size_t)wm * D * D;
  u16* Om = WT + (size_t)wm * 896 * D;
  const int tx = threadIdx.x, ty = threadIdx.y;
#pragma unroll
  for (int i = ty; i < 32; i += 8) {
    const int n = n0 + tx;
    t[i][tx] = (n < D) ? f2b(Wm[(size_t)(k0 + i) * D + n]) : (u16)0;
  }
  __syncthreads();
#pragma unroll
  for (int i = ty; i < 32; i += 8) {
    Om[(size_t)(n0 + i) * D + (k0 + tx)] = t[tx][i];
  }
}

// ------ e_pre[b] += Ah[ba0] + Ah[ba1] + Cu[bg]  (in-place, ushort8/lane) ----
__global__ __launch_bounds__(256) void bond_combine(
    u16* __restrict__ epre, const u16* __restrict__ Ah, const u16* __restrict__ Cu,
    const int* __restrict__ ba, const int* __restrict__ bg)
{
  const int t = blockIdx.x * 256 + threadIdx.x;
  if (t >= NB * 100) return;
  const int b = t / 100;
  const int c = t - b * 100;
  const int a0 = ba[b * 2], a1 = ba[b * 2 + 1], g = bg[b];
  const size_t off = (size_t)c * 8;
  u16* re = epre + (size_t)b * D + off;
  const s8v ve = *(const s8v*)re;
  const s8v v0 = *(const s8v*)(Ah + (size_t)a0 * D + off);
  const s8v v1 = *(const s8v*)(Ah + (size_t)a1 * D + off);
  const s8v vg = *(const s8v*)(Cu + (size_t)g * D + off);
  s8v o;
#pragma unroll
  for (int l = 0; l < 8; ++l)
    o[l] = (short)f2b(b2f((u16)ve[l]) + b2f((u16)v0[l]) + b2f((u16)v1[l]) + b2f((u16)vg[l]));
  *(s8v*)re = o;
}

// ------- two-stage column stats: partial (no atomics) + final reduce --------
__global__ __launch_bounds__(128) void col_part(
    const u16* __restrict__ x, int M, int rpb, float* __restrict__ part)
{
  const int c = threadIdx.x;
  if (c >= 100) return;
  const int r0 = blockIdx.y * rpb;
  int r1 = r0 + rpb; if (r1 > M) r1 = M;
  float s[8] = {}, ss[8] = {};
  for (int r = r0; r < r1; ++r) {
    const s8v v = *(const s8v*)(x + (size_t)r * D + c * 8);
#pragma unroll
    for (int l = 0; l < 8; ++l) { const float f = b2f((u16)v[l]); s[l] += f; ss[l] += f * f; }
  }
  float* p = part + (size_t)blockIdx.y * 1600 + c * 8;
#pragma unroll
  for (int l = 0; l < 8; ++l) { p[l] = s[l]; p[800 + l] = ss[l]; }
}

__global__ __launch_bounds__(256) void col_fin(
    const float* __restrict__ part, int ny, float* __restrict__ sums)
{
  const int idx = blockIdx.x * 256 + threadIdx.x;
  if (idx >= 1600) return;
  float s = 0.f;
  for (int y = 0; y < ny; ++y) s += part[(size_t)y * 1600 + idx];
  sums[idx] = s;
}

// ---------------- legacy column sums (kept for small f32 u-path) ------------
__global__ __launch_bounds__(256) void col_stats(
    const void* __restrict__ x, int isf32, int M, int rpb, float* __restrict__ sums)
{
  const int col = blockIdx.x * 256 + threadIdx.x;
  if (col >= D) return;
  const int r0 = blockIdx.y * rpb;
  int r1 = r0 + rpb; if (r1 > M) r1 = M;
  float s = 0.f, ss = 0.f;
  if (isf32) {
    const float* xf = (const float*)x;
    for (int r = r0; r < r1; ++r) { const float v = xf[(size_t)r * D + col]; s += v; ss += v * v; }
  } else {
    const u16* xb = (const u16*)x;
    for (int r = r0; r < r1; ++r) { const float v = b2f(xb[(size_t)r * D + col]); s += v; ss += v * v; }
  }
  atomicAdd(&sums[col], s);
  atomicAdd(&sums[D + col], ss);
}

// ---- bn+relu, thread owns 8 cols: ushort8 in, 2x float4 out ----------------
__global__ __launch_bounds__(128) void bn_relu8(
    const u16* __restrict__ x, int M, int rpb, const float* __restrict__ sums,
    const float* __restrict__ gamma, const float* __restrict__ beta, float* __restrict__ out)
{
  const int c = threadIdx.x;
  if (c >= 100) return;
  const float invM = 1.f / (float)M;
  float gg[8], bb[8];
#pragma unroll
  for (int l = 0; l < 8; ++l) {
    const int col = c * 8 + l;
    const float mean = sums[col] * invM;
    float var = sums[800 + col] * invM - mean * mean;
    if (var < 0.f) var = 0.f;
    const float rs = rsqrtf(var + 1e-5f);
    gg[l] = gamma[col] * rs;
    bb[l] = beta[col] - mean * gg[l];
  }
  const int r0 = blockIdx.y * rpb;
  int r1 = r0 + rpb; if (r1 > M) r1 = M;
  for (int r = r0; r < r1; ++r) {
    const s8v v = *(const s8v*)(x + (size_t)r * D + c * 8);
    f4v o0, o1;
#pragma unroll
    for (int l = 0; l < 4; ++l) {
      const float y0 = b2f((u16)v[l]) * gg[l] + bb[l];
      o0[l] = (y0 > 0.f) ? y0 : 0.f;
      const float y1 = b2f((u16)v[4 + l]) * gg[4 + l] + bb[4 + l];
      o1[l] = (y1 > 0.f) ? y1 : 0.f;
    }
    float* orow = out + (size_t)r * D + c * 8;
    *(f4v*)orow = o0;
    *(f4v*)(orow + 4) = o1;
  }
}

// ---------------- legacy bn_relu (kept for small f32 u-path) ----------------
__global__ __launch_bounds__(256) void bn_relu(
    const void* __restrict__ x, int isf32, int M, int rpb, const float* __restrict__ sums,
    const float* __restrict__ gamma, const float* __restrict__ beta, float* __restrict__ out)
{
  const int col = blockIdx.x * 256 + threadIdx.x;
  if (col >= D) return;
  const float invM = 1.f / (float)M;
  const float mean = sums[col] * invM;
  float var = sums[D + col] * invM - mean * mean;
  if (var < 0.f) var = 0.f;
  const float rs = rsqrtf(var + 1e-5f);
  const float g = gamma[col] * rs;
  const float b = beta[col] - mean * g;
  const int r0 = blockIdx.y * rpb;
  int r1 = r0 + rpb; if (r1 > M) r1 = M;
  if (isf32) {
    const float* xf = (const float*)x;
    for (int r = r0; r < r1; ++r) {
      const float y = xf[(size_t)r * D + col] * g + b;
      out[(size_t)r * D + col] = (y > 0.f) ? y : 0.f;
    }
  } else {
    const u16* xb = (const u16*)x;
    for (int r = r0; r < r1; ++r) {
      const float y = b2f(xb[(size_t)r * D + col]) * g + b;
      out[(size_t)r * D + col] = (y > 0.f) ? y : 0.f;
    }
  }
}

// ------- gated mailbox aggregation + a2a + g2a (thread owns 4 cols) ---------
__global__ __launch_bounds__(256) void atom_update(
    u16* __restrict__ hpre, const u16* __restrict__ Dh, const u16* __restrict__ Eh,
    const float* __restrict__ en, const u16* __restrict__ Fu,
    const int* __restrict__ ab, const int* __restrict__ ba, const int* __restrict__ ag)
{
  const int i = blockIdx.x;
  __shared__ int sb[4], so[4], sg[1];
  const int t = threadIdx.x;
  if (t < 4) {
    const int b = ab[i * 4 + t];
    sb[t] = b;
    const int p0 = ba[b * 2], p1 = ba[b * 2 + 1];
    so[t] = (p0 != i) ? p0 : p1;
  }
  if (t == 4) sg[0] = ag[i];
  __syncthreads();
  if (t >= 200) return;
  const int j0 = t * 4;
  float num[4] = {0.f, 0.f, 0.f, 0.f}, den[4] = {0.f, 0.f, 0.f, 0.f};
#pragma unroll
  for (int k = 0; k < 4; ++k) {
    const f4v ev = *(const f4v*)(en + (size_t)sb[k] * D + j0);
    const s4v eo = *(const s4v*)(Eh + (size_t)so[k] * D + j0);
#pragma unroll
    for (int l = 0; l < 4; ++l) {
      const float s = 1.f / (1.f + __expf(-ev[l]));
      num[l] += s * b2f((u16)eo[l]);
      den[l] += s;
    }
  }
  const s4v dv = *(const s4v*)(Dh + (size_t)i * D + j0);
  const s4v fv = *(const s4v*)(Fu + (size_t)sg[0] * D + j0);
  s4v o;
#pragma unroll
  for (int l = 0; l < 4; ++l)
    o[l] = (short)f2b(b2f((u16)dv[l]) + num[l] / (den[l] + 1e-6f) + b2f((u16)fv[l]));
  *(s4v*)(hpre + (size_t)i * D + j0) = o;
}

// --- c = 1/(|d1-d2|+1); cd1 = c*d1; cd2 = c*d2 (ushort8/lane) ---------------
__global__ __launch_bounds__(256) void cross_cd(
    const u16* __restrict__ D1, const u16* __restrict__ D2,
    u16* __restrict__ c1, u16* __restrict__ c2)
{
  const int t = blockIdx.x * 256 + threadIdx.x;
  if (t >= NA * 100) return;
  const size_t off = (size_t)t * 8;
  const s8v v1 = *(const s8v*)(D1 + off);
  const s8v v2 = *(const s8v*)(D2 + off);
  s8v o1, o2;
#pragma unroll
  for (int l = 0; l < 8; ++l) {
    const float d1 = b2f((u16)v1[l]), d2 = b2f((u16)v2[l]);
    const float cc = 1.f / (fabsf(d1 - d2) + 1.f);
    o1[l] = (short)f2b(cc * d1);
    o2[l] = (short)f2b(cc * d2);
  }
  *(s8v*)(c1 + off) = o1;
  *(s8v*)(c2 + off) = o2;
}

// ============ counting-sort based segment mean (4 pipelines fused) ==========
__global__ void seg_histo(const int* __restrict__ s0, const int* __restrict__ s1,
                          const int* __restrict__ s2, const int* __restrict__ s3,
                          int* __restrict__ cnt) {
  const int which = blockIdx.y;
  const int* s = (which == 0) ? s0 : (which == 1) ? s1 : (which == 2) ? s2 : s3;
  const int n = (which < 2) ? NA : NB;
  const int i = blockIdx.x * 256 + threadIdx.x;
  if (i < n) atomicAdd(&cnt[which * NG + s[i]], 1);
}

__global__ __launch_bounds__(256) void seg_scan(
    const int* __restrict__ cnt, int* __restrict__ start, int* __restrict__ cursor) {
  const int which = blockIdx.x;
  __shared__ int buf[NG];
  const int t = threadIdx.x;
  const int v = cnt[which * NG + t];
  buf[t] = v;
  __syncthreads();
  int sum = 0;
  for (int i = 0; i < t; ++i) sum += buf[i];
  start[which * 257 + t] = sum;
  cursor[which * NG + t] = sum;
  if (t == NG - 1) start[which * 257 + NG] = sum + v;
}

__global__ void seg_scatter(const int* __restrict__ s0, const int* __restrict__ s1,
                            const int* __restrict__ s2, const int* __restrict__ s3,
                            int* __restrict__ cursor, int* __restrict__ order) {
  const int which = blockIdx.y;
  const int* s = (which == 0) ? s0 : (which == 1) ? s1 : (which == 2) ? s2 : s3;
  const int n = (which < 2) ? NA : NB;
  const int i = blockIdx.x * 256 + threadIdx.x;
  if (i < n) {
    const int pos = atomicAdd(&cursor[which * NG + s[i]], 1);
    order[which * NB + pos] = i;
  }
}

__global__ __launch_bounds__(256) void seg_reduce(
    const float* __restrict__ x0, const float* __restrict__ x1,
    const float* __restrict__ x2, const float* __restrict__ x3,
    const int* __restrict__ order, const int* __restrict__ start,
    float* __restrict__ means) {
  const int which = blockIdx.y;
  const float* x = (which == 0) ? x0 : (which == 1) ? x1 : (which == 2) ? x2 : x3;
  const int* ord = order + which * NB;
  const int g = blockIdx.x;
  const int i0 = start[which * 257 + g];
  const int i1 = start[which * 257 + g + 1];
  const int t = threadIdx.x;
  if (t >= 200) return;
  float a0 = 0.f, a1 = 0.f, a2 = 0.f, a3 = 0.f;
  for (int i = i0; i < i1; ++i) {
    const f4v v = *(const f4v*)(x + (size_t)ord[i] * D + t * 4);
    a0 += v[0]; a1 += v[1]; a2 += v[2]; a3 += v[3];
  }
  const int cc = i1 - i0;
  const float inv = 1.f / (float)(cc > 1 ? cc : 1);
  f4v o; o[0] = a0 * inv; o[1] = a1 * inv; o[2] = a2 * inv; o[3] = a3 * inv;
  *(f4v*)(means + ((size_t)which * NG + g) * D + t * 4) = o;
}

__global__ __launch_bounds__(256) void bar_prep(
    const float* __restrict__ means, u16* __restrict__ hbar, u16* __restrict__ ebar) {
  const int i4 = blockIdx.x * 256 + threadIdx.x;
  if (i4 >= NG * 200) return;
  const f4v m1 = ((const f4v*)means)[i4];
  const f4v m2 = ((const f4v*)(means + (size_t)NG * D))[i4];
  const f4v e1 = ((const f4v*)(means + (size_t)2 * NG * D))[i4];
  const f4v e2 = ((const f4v*)(means + (size_t)3 * NG * D))[i4];
  ushort4 ho, eo;
  ho.x = f2b(m1[0] + m2[0]); ho.y = f2b(m1[1] + m2[1]);
  ho.z = f2b(m1[2] + m2[2]); ho.w = f2b(m1[3] + m2[3]);
  eo.x = f2b(e1[0] + e2[0]); eo.y = f2b(e1[1] + e2[1]);
  eo.z = f2b(e1[2] + e2[2]); eo.w = f2b(e1[3] + e2[3]);
  ((ushort4*)hbar)[i4] = ho;
  ((ushort4*)ebar)[i4] = eo;
}

extern "C" void kernel_launch(void* const* d_in, const int* in_sizes, int n_in,
                              void* d_out, int out_size, void* d_ws, size_t ws_size,
                              hipStream_t stream)
{
  const float* h   = (const float*)d_in[0];
  const float* e   = (const float*)d_in[1];
  const float* h2  = (const float*)d_in[2];
  const float* e2  = (const float*)d_in[3];
  const float* u   = (const float*)d_in[4];
  const float* Ws  = (const float*)d_in[5];
  const float* bs  = (const float*)d_in[6];
  const float* gm  = (const float*)d_in[7];
  const float* bt  = (const float*)d_in[8];
  const int* ba1 = (const int*)d_in[9];
  const int* ab1 = (const int*)d_in[10];
  const int* ag1 = (const int*)d_in[11];
  const int* bg1 = (const int*)d_in[12];
  const int* ba2 = (const int*)d_in[13];
  const int* ab2 = (const int*)d_in[14];
  const int* ag2 = (const int*)d_in[15];
  const int* bg2 = (const int*)d_in[16];
  char* ws = (char*)d_ws;
  char* ob = (char*)d_out;

  // ---- workspace layout (bytes) ----
  const size_t WT   = 0;                    // 14,336,000
  const size_t CB   = 14336000;             // 38,400,000 cast buf A / cd1 / sort
  const size_t E1P  = 52736000;             // 38,400,000 e1p (later h1pre)
  const size_t E2P  = 91136000;             // 38,400,000 cbh2 -> e2p (later h2pre)
  const size_t CD2  = 129536000;            // 32,000,000
  const size_t CUo  = 161536000;
  const size_t FUo  = 161945600;
  const size_t UB   = 162355200;
  const size_t F32Z = 162764800;            // zeroed fp32 scratch base
  const size_t ST_E1 = F32Z;
  const size_t ST_E2 = F32Z + 6400;
  const size_t ST_H1 = F32Z + 12800;
  const size_t ST_H2 = F32Z + 19200;
  const size_t ST_U  = F32Z + 25600;
  const size_t ZLEN  = 32000;
  const size_t MEANS = F32Z + 32000;        // 3,276,800
  const size_t HBAR  = MEANS + 3276800;     // 409,600 (GEMM-A: backed by EBAR)
  const size_t EBAR  = HBAR + 409600;       // 409,600 (GEMM-A: backed by UPRE)
  const size_t UPRE  = EBAR + 409600;       // 819,200
  // sort scratch inside CB region (dead after the mode-1 GEMMs)
  const size_t ORD  = CB;
  const size_t CNTI = CB + 400000;
  const size_t STRT = CB + 404496 + 3504;
  const size_t CURS = CB + 416000;
  const size_t PART = CB + 4000000;         // e-path col-stat partials

  u16* wt  = (u16*)(ws + WT);
  u16* cb  = (u16*)(ws + CB);
  u16* e1p = (u16*)(ws + E1P);
  u16* e2p = (u16*)(ws + E2P);
  u16* cbh2 = e2p;                          // h2 cast buffer (dead before e2p)
  u16* cd2 = (u16*)(ws + CD2);
  u16* cu  = (u16*)(ws + CUo);
  u16* fu  = (u16*)(ws + FUo);
  u16* ub  = (u16*)(ws + UB);
  u16* h1p = e1p;
  u16* h2p = e2p;
  u16* cd1 = cb;
  float* part = (float*)(ws + PART);

  float* o_h1 = (float*)ob;
  float* o_e1 = (float*)(ob + 64000000);
  float* o_h2 = (float*)(ob + 140800000);
  float* o_e2 = (float*)(ob + 204800000);
  float* o_u  = (float*)(ob + 281600000);
  u16* eh1s = (u16*)ob;
  u16* dh1s = (u16*)(ob + 32000000);
  u16* eh2s = (u16*)(ob + 140800000);
  u16* dh2s = (u16*)(ob + 172800000);
  u16* ah1s = (u16*)(ob + 64000000);
  u16* ah2s = (u16*)(ob + 204800000);

  auto launch = [&](int rt, int ny, const u16* A0, const u16* A1, int M, int mode,
                    float bsc, u16* o0, u16* o1, u16* o2, u16* o3, u16* o4, u16* o5,
                    float* outf, u16* pv0, u16* pv1, float* s0, float* s1,
                    int nwh, int w0, int w1, int w2) {
    gemm_bt<<<dim3((unsigned)rt, (unsigned)ny), 256, 0, stream>>>(
        A0, A1, wt, bs, M, mode, bsc, o0, o1, o2, o3, o4, o5,
        outf, pv0, pv1, s0, s1, nwh, w0, w1, w2);
  };

  hipMemsetAsync(ws + F32Z, 0, ZLEN, stream);
  transpose_w<<<dim3(25, 28, 10), dim3(32, 8), 0, stream>>>(Ws, wt);

  // u-linears (Cu + Fu in one batched launch)
  castk<<<200, 256, 0, stream>>>(u, ub, NG * D / 4);
  launch(2, 14, ub, nullptr, NG, 0, 1.f, cu, fu, nullptr, nullptr, nullptr, nullptr,
         nullptr, nullptr, nullptr, nullptr, nullptr, 2, 2, 5, 0);

  // h/h2 linears: 6 GEMMs in ONE batched launch (A/D/E x both halves)
  castk<<<15625, 256, 0, stream>>>(h, cb, NA * D / 4);
  castk<<<15625, 256, 0, stream>>>(h2, cbh2, NA * D / 4);
  launch(157, 42, cb, cbh2, NA, 0, 1.f, ah1s, dh1s, eh1s, ah2s, dh2s, eh2s,
         nullptr, nullptr, nullptr, nullptr, nullptr, 3, 0, 3, 4);

  // e linears (sequential: single cast buffer)
  castk<<<18750, 256, 0, stream>>>(e, cb, NB * D / 4);
  launch(188, 7, cb, nullptr, NB, 0, 1.f, e1p, nullptr, nullptr, nullptr, nullptr,
         nullptr, nullptr, nullptr, nullptr, nullptr, nullptr, 1, 1, 0, 0);
  castk<<<18750, 256, 0, stream>>>(e2, cb, NB * D / 4);
  launch(188, 7, cb, nullptr, NB, 0, 1.f, e2p, nullptr, nullptr, nullptr, nullptr,
         nullptr, nullptr, nullptr, nullptr, nullptr, nullptr, 1, 1, 0, 0);

  // bond update + BN + relu -> e1n/e2n
  bond_combine<<<9375, 256, 0, stream>>>(e1p, ah1s, cu, ba1, bg1);
  bond_combine<<<9375, 256, 0, stream>>>(e2p, ah2s, cu, ba2, bg2);
  col_part<<<dim3(1, 500), 128, 0, stream>>>(e1p, NB, 48, part);
  col_fin<<<7, 256, 0, stream>>>(part, 500, (float*)(ws + ST_E1));
  col_part<<<dim3(1, 500), 128, 0, stream>>>(e2p, NB, 48, part);
  col_fin<<<7, 256, 0, stream>>>(part, 500, (float*)(ws + ST_E2));
  bn_relu8<<<dim3(1, 500), 128, 0, stream>>>(e1p, NB, 48, (float*)(ws + ST_E1), gm, bt, o_e1);
  bn_relu8<<<dim3(1, 500), 128, 0, stream>>>(e2p, NB, 48, (float*)(ws + ST_E2), gm, bt, o_e2);

  // atom update
  atom_update<<<NA, 256, 0, stream>>>(h1p, dh1s, eh1s, o_e1, fu, ab1, ba1, ag1);
  atom_update<<<NA, 256, 0, stream>>>(h2p, dh2s, eh2s, o_e2, fu, ab2, ba2, ag2);

  // cross messages: both mode-1 GEMMs batched, h-col-stats fused into epilogue
  cross_cd<<<7813, 256, 0, stream>>>(dh1s, dh2s, cd1, cd2);
  launch(157, 14, cd2, cd1, NA, 1, 1.f, nullptr, nullptr, nullptr, nullptr, nullptr,
         nullptr, nullptr, h1p, h2p, (float*)(ws + ST_H1), (float*)(ws + ST_H2),
         1, 9, 0, 0);

  // BN + relu -> h1n/h2n (stats already accumulated by the GEMM epilogue)
  bn_relu8<<<dim3(1, 500), 128, 0, stream>>>(h1p, NA, 40, (float*)(ws + ST_H1), gm + D, bt + D, o_h1);
  bn_relu8<<<dim3(1, 500), 128, 0, stream>>>(h2p, NA, 40, (float*)(ws + ST_H2), gm + D, bt + D, o_h2);

  // segment means via counting sort (CB region is dead now)
  hipMemsetAsync(ws + CNTI, 0, 4096, stream);
  seg_histo<<<dim3(94, 4), 256, 0, stream>>>(ag1, ag2, bg1, bg2, (int*)(ws + CNTI));
  seg_scan<<<4, 256, 0, stream>>>((int*)(ws + CNTI), (int*)(ws + STRT), (int*)(ws + CURS));
  seg_scatter<<<dim3(94, 4), 256, 0, stream>>>(ag1, ag2, bg1, bg2,
                                               (int*)(ws + CURS), (int*)(ws + ORD));
  seg_reduce<<<dim3(NG, 4), 256, 0, stream>>>(o_h1, o_h2, o_e1, o_e2,
                                              (int*)(ws + ORD), (int*)(ws + STRT),
                                              (float*)(ws + MEANS));
  bar_prep<<<200, 256, 0, stream>>>((float*)(ws + MEANS), (u16*)(ws + HBAR), (u16*)(ws + EBAR));

  // u_pre = u@W8 + b8 + hbar12@W6 + 2*b6 + ebar12@W7 + 2*b7 (fp32 accum)
  launch(2, 7, ub, nullptr, NG, 2, 1.f, nullptr, nullptr, nullptr, nullptr, nullptr,
         nullptr, (float*)(ws + UPRE), nullptr, nullptr, nullptr, nullptr, 1, 8, 0, 0);
  launch(2, 7, (u16*)(ws + HBAR), nullptr, NG, 3, 2.f, nullptr, nullptr, nullptr,
         nullptr, nullptr, nullptr, (float*)(ws + UPRE), nullptr, nullptr, nullptr,
         nullptr, 1, 6, 0, 0);
  launch(2, 7, (u16*)(ws + EBAR), nullptr, NG, 3, 2.f, nullptr, nullptr, nullptr,
         nullptr, nullptr, nullptr, (float*)(ws + UPRE), nullptr, nullptr, nullptr,
         nullptr, 1, 7, 0, 0);

  col_stats<<<dim3(4, 1), 256, 0, stream>>>((float*)(ws + UPRE), 1, NG, 256, (float*)(ws + ST_U));
  bn_relu<<<dim3(4, 1), 256, 0, stream>>>((float*)(ws + UPRE), 1, NG, 256, (float*)(ws + ST_U),
                                          gm + 2 * D, bt + 2 * D, o_u);
}